// Round 1
// baseline (5252.221 us; speedup 1.0000x reference)
//
#include <hip/hip_runtime.h>
#include <math.h>
#include <stdint.h>

#define IMG_SZ 800.0f
#define NPIX 2500
#define NANC 22500
#define PRE_NMS 6000
#define NROI 128
#define BBOX_CLIP 4.135166556742356f

// ---------------- workspace layout (float offsets) ----------------
constexpr int OFF_H      = 0;                         // 512*2500 conv output
constexpr int OFF_CLS    = OFF_H + 512 * NPIX;        // 18*2500
constexpr int OFF_REG    = OFF_CLS + 18 * NPIX;       // 36*2500
constexpr int OFF_SCORE  = OFF_REG + 36 * NPIX;       // 22500
constexpr int OFF_PBOX   = OFF_SCORE + NANC;          // 22500*4
constexpr int OFF_POOLS  = OFF_PBOX + NANC * 4;       // 6144 pool scores
constexpr int OFF_POOLB  = OFF_POOLS + 6144;          // 6144*4 pool boxes
constexpr int OFF_POOLI  = OFF_POOLB + 6144 * 4;      // 6144 pool orig idx (int)
constexpr int OFF_CNT    = OFF_POOLI + 6144;          // 4 (int count)
constexpr int OFF_ROIS   = OFF_CNT + 4;               // 128*4
constexpr int OFF_OK     = OFF_ROIS + 512;            // 128
constexpr int OFF_WT     = OFF_OK + 128;              // 4608*512 transposed conv w
constexpr int OFF_POOLED = OFF_WT + 4608 * 512;       // 128*25088
constexpr int OFF_X1     = OFF_POOLED + 128 * 25088;  // 128*4096
constexpr int OFF_X2     = OFF_X1 + 128 * 4096;       // 128*4096

// ---------------- K0: conv weight transpose [oc][ic*9+tap] -> [(tap*512+ic)][oc] ----
__global__ __launch_bounds__(256) void k0_transpose(const float* __restrict__ w,
                                                    float* __restrict__ wt) {
    __shared__ float tile[64][65];
    const int kt = blockIdx.x;   // 0..71 over kin = ic*9+tap
    const int ot = blockIdx.y;   // 0..7 over oc
    const int t = threadIdx.x;
#pragma unroll
    for (int i = 0; i < 16; ++i) {
        int l = t + i * 256;
        int r = l >> 6;     // oc local
        int c = l & 63;     // kin local
        tile[r][c] = w[(ot * 64 + r) * 4608 + kt * 64 + c];
    }
    __syncthreads();
#pragma unroll
    for (int i = 0; i < 16; ++i) {
        int l = t + i * 256;
        int r = l >> 6;     // kin local
        int c = l & 63;     // oc local
        int kin = kt * 64 + r;
        int k = (kin % 9) * 512 + (kin / 9);   // tap*512 + ic
        wt[k * 512 + ot * 64 + c] = tile[c][r];
    }
}

// ---------------- K1: 3x3 conv 512->512 + bias + relu (implicit GEMM) ----------------
__global__ __launch_bounds__(256) void k1_conv(const float* __restrict__ feat,
                                               const float* __restrict__ wt,
                                               const float* __restrict__ bias,
                                               float* __restrict__ h) {
    __shared__ float As[16][64];
    __shared__ float Bs[16][64];
    const int pt = blockIdx.x;   // pixel tile 0..39 (64 px each)
    const int ot = blockIdx.y;   // oc tile 0..7   (64 oc each)
    const int t = threadIdx.x;
    const int tx = t & 15, ty = t >> 4;
    float acc[4][4];
#pragma unroll
    for (int i = 0; i < 4; ++i)
#pragma unroll
        for (int j = 0; j < 4; ++j) acc[i][j] = 0.f;

    for (int cc = 0; cc < 288; ++cc) {            // 9 taps * 32 ic-chunks of 16
        const int tap = cc >> 5;
        const int ic0 = (cc & 31) << 4;
        const int ky = tap / 3 - 1, kx = tap % 3 - 1;
#pragma unroll
        for (int i = 0; i < 4; ++i) {
            int l = t + i * 256;
            int kk = l >> 6, oc = l & 63;
            As[kk][oc] = wt[(tap * 512 + ic0 + kk) * 512 + ot * 64 + oc];
        }
#pragma unroll
        for (int i = 0; i < 4; ++i) {
            int l = t + i * 256;
            int kk = l >> 6, px = l & 63;
            int p = pt * 64 + px;
            int y = p / 50, x = p - y * 50;
            int sy = y + ky, sx = x + kx;
            float v = 0.f;
            if (p < 2500 && (unsigned)sy < 50u && (unsigned)sx < 50u)
                v = feat[(ic0 + kk) * 2500 + sy * 50 + sx];
            Bs[kk][px] = v;
        }
        __syncthreads();
#pragma unroll
        for (int kk = 0; kk < 16; ++kk) {
            float4 a4 = *(const float4*)&As[kk][ty * 4];
            float4 b4 = *(const float4*)&Bs[kk][tx * 4];
            float av[4] = {a4.x, a4.y, a4.z, a4.w};
            float bv[4] = {b4.x, b4.y, b4.z, b4.w};
#pragma unroll
            for (int i = 0; i < 4; ++i)
#pragma unroll
                for (int j = 0; j < 4; ++j)
                    acc[i][j] = fmaf(av[i], bv[j], acc[i][j]);
        }
        __syncthreads();
    }
    const int p0 = pt * 64 + tx * 4;
    if (p0 < 2500) {
#pragma unroll
        for (int i = 0; i < 4; ++i) {
            int oc = ot * 64 + ty * 4 + i;
            float bv = bias[oc];
            float4 o;
            o.x = fmaxf(acc[i][0] + bv, 0.f);
            o.y = fmaxf(acc[i][1] + bv, 0.f);
            o.z = fmaxf(acc[i][2] + bv, 0.f);
            o.w = fmaxf(acc[i][3] + bv, 0.f);
            *(float4*)&h[oc * 2500 + p0] = o;
        }
    }
}

// ---------------- K2: 1x1 convs (18 cls + 36 reg channels) ----------------
__global__ __launch_bounds__(256) void k2_rpnhead(const float* __restrict__ h,
                                                  const float* __restrict__ wc,
                                                  const float* __restrict__ bc,
                                                  const float* __restrict__ wr,
                                                  const float* __restrict__ br,
                                                  float* __restrict__ outcls,
                                                  float* __restrict__ outreg) {
    __shared__ float smem[54][129];
    const int id = blockIdx.x * 256 + threadIdx.x;
    const int p = id / 54, o = id % 54;
    const bool active = (id < 54 * NPIX);
    float acc = 0.f;
    for (int c0 = 0; c0 < 512; c0 += 128) {
        for (int l = threadIdx.x; l < 54 * 128; l += 256) {
            int oo = l >> 7, ccx = l & 127;
            smem[oo][ccx] = (oo < 18) ? wc[oo * 512 + c0 + ccx]
                                      : wr[(oo - 18) * 512 + c0 + ccx];
        }
        __syncthreads();
        if (active) {
#pragma unroll 4
            for (int ccx = 0; ccx < 128; ++ccx)
                acc = fmaf(h[(c0 + ccx) * 2500 + p], smem[o][ccx], acc);
        }
        __syncthreads();
    }
    if (active) {
        if (o < 18) outcls[o * 2500 + p] = acc + bc[o];
        else        outreg[(o - 18) * 2500 + p] = acc + br[o - 18];
    }
}

// ---------------- K3: softmax score + proposal decode + clip ----------------
__global__ void k3_decode(const float* __restrict__ cls, const float* __restrict__ reg,
                          const float* __restrict__ anch,
                          float* __restrict__ score, float* __restrict__ pbox) {
    const int i = blockIdx.x * 256 + threadIdx.x;
    if (i >= NANC) return;
    const int p = i / 9, a = i % 9;
    float l0 = cls[(a * 2 + 0) * 2500 + p];
    float l1 = cls[(a * 2 + 1) * 2500 + p];
    score[i] = 1.f / (1.f + expf(l0 - l1));   // softmax(...)[1]
    float d0 = reg[(a * 4 + 0) * 2500 + p];
    float d1 = reg[(a * 4 + 1) * 2500 + p];
    float d2 = reg[(a * 4 + 2) * 2500 + p];
    float d3 = reg[(a * 4 + 3) * 2500 + p];
    float a0 = anch[i * 4 + 0], a1 = anch[i * 4 + 1];
    float a2 = anch[i * 4 + 2], a3 = anch[i * 4 + 3];
    float hh = a2 - a0, ww = a3 - a1;
    float cy = a0 + 0.5f * hh, cx = a1 + 0.5f * ww;
    float dh = fminf(fmaxf(d2, -BBOX_CLIP), BBOX_CLIP);
    float dw = fminf(fmaxf(d3, -BBOX_CLIP), BBOX_CLIP);
    float pcy = cy + d0 * hh, pcx = cx + d1 * ww;
    float ph = hh * expf(dh), pw = ww * expf(dw);
    float b0 = pcy - 0.5f * ph, b1 = pcx - 0.5f * pw;
    float b2 = pcy + 0.5f * ph, b3 = pcx + 0.5f * pw;
    b0 = fminf(fmaxf(b0, 0.f), IMG_SZ);
    b1 = fminf(fmaxf(b1, 0.f), IMG_SZ);
    b2 = fminf(fmaxf(b2, 0.f), IMG_SZ);
    b3 = fminf(fmaxf(b3, 0.f), IMG_SZ);
    pbox[i * 4 + 0] = b0; pbox[i * 4 + 1] = b1;
    pbox[i * 4 + 2] = b2; pbox[i * 4 + 3] = b3;
}

// ---------------- K4a: exact top-6000 pool select (radix histogram) ----------------
__global__ __launch_bounds__(1024) void k4a_select(const float* __restrict__ score,
                                                   const float* __restrict__ pbox,
                                                   float* __restrict__ pools,
                                                   float* __restrict__ poolb,
                                                   int* __restrict__ pooli,
                                                   int* __restrict__ cntout) {
    __shared__ unsigned hist[2048];
    __shared__ unsigned sv[8];
    __shared__ int eqlist[2048];
    __shared__ unsigned eqn, cnt;
    const int t = threadIdx.x;
    // level 1: bits >> 21
    hist[t] = 0; hist[t + 1024] = 0;
    if (t == 0) { eqn = 0; cnt = 0; }
    __syncthreads();
    for (int j = t; j < NANC; j += 1024) {
        unsigned u = __float_as_uint(score[j]);
        atomicAdd(&hist[u >> 21], 1u);
    }
    __syncthreads();
    if (t == 0) {
        unsigned cum = 0; int b = 2047;
        for (; b >= 0; --b) { cum += hist[b]; if (cum >= PRE_NMS) break; }
        sv[0] = (unsigned)b; sv[1] = PRE_NMS - (cum - hist[b]);
    }
    __syncthreads();
    const unsigned b1 = sv[0], rank1 = sv[1];
    // level 2: bits[20:10] within b1
    hist[t] = 0; hist[t + 1024] = 0;
    __syncthreads();
    for (int j = t; j < NANC; j += 1024) {
        unsigned u = __float_as_uint(score[j]);
        if ((u >> 21) == b1) atomicAdd(&hist[(u >> 10) & 0x7FFu], 1u);
    }
    __syncthreads();
    if (t == 0) {
        unsigned cum = 0; int b = 2047;
        for (; b >= 0; --b) { cum += hist[b]; if (cum >= rank1) break; }
        sv[2] = (unsigned)b; sv[3] = rank1 - (cum - hist[b]);
    }
    __syncthreads();
    const unsigned b2 = sv[2], rank2 = sv[3];
    const unsigned hi21 = (b1 << 11) | b2;
    // level 3: bits[9:0] within (b1,b2)
    hist[t] = 0; hist[t + 1024] = 0;
    __syncthreads();
    for (int j = t; j < NANC; j += 1024) {
        unsigned u = __float_as_uint(score[j]);
        if ((u >> 10) == hi21) atomicAdd(&hist[u & 0x3FFu], 1u);
    }
    __syncthreads();
    if (t == 0) {
        unsigned cum = 0; int b = 1023;
        for (; b >= 0; --b) { cum += hist[b]; if (cum >= rank2) break; }
        sv[4] = (hi21 << 10) | (unsigned)b;      // exact threshold bits T
        sv[5] = rank2 - (cum - hist[b]);         // need_eq
        sv[6] = hist[b];                          // n_eq
    }
    __syncthreads();
    const unsigned T = sv[4], need_eq = sv[5], n_eq = sv[6];
    // tie list (ties by smaller original index first)
    if (n_eq != need_eq) {
        for (int j = t; j < NANC; j += 1024) {
            if (__float_as_uint(score[j]) == T) {
                unsigned pos = atomicAdd(&eqn, 1u);
                if (pos < 2048u) eqlist[pos] = j;
            }
        }
    }
    __syncthreads();
    const unsigned neq = eqn < 2048u ? eqn : 2048u;
    // compaction (pool order irrelevant; argmax key carries orig index)
    for (int j = t; j < NANC; j += 1024) {
        float s = score[j];
        unsigned u = __float_as_uint(s);
        bool take = false;
        if (u > T) take = true;
        else if (u == T) {
            if (n_eq == need_eq) take = true;
            else {
                unsigned less = 0;
                for (unsigned q = 0; q < neq; ++q)
                    if ((unsigned)eqlist[q] < (unsigned)j) ++less;
                take = (less < need_eq);
            }
        }
        if (take) {
            unsigned pos = atomicAdd(&cnt, 1u);
            if (pos < 6144u) {
                pools[pos] = s;
                pooli[pos] = j;
                poolb[pos * 4 + 0] = pbox[j * 4 + 0];
                poolb[pos * 4 + 1] = pbox[j * 4 + 1];
                poolb[pos * 4 + 2] = pbox[j * 4 + 2];
                poolb[pos * 4 + 3] = pbox[j * 4 + 3];
            }
        }
    }
    __syncthreads();
    if (t == 0) *cntout = (int)(cnt < 6144u ? cnt : 6144u);
}

// ---------------- K4b: greedy NMS (128 selections), pool in registers ----------------
__global__ __launch_bounds__(1024) void k4b_nms(const float* __restrict__ pools,
                                                const float* __restrict__ poolb,
                                                const int* __restrict__ pooli,
                                                const int* __restrict__ cntp,
                                                float* __restrict__ rois,
                                                float* __restrict__ okf) {
    __shared__ float wvS[16];
    __shared__ int wvI[16];
    __shared__ float selS; __shared__ int selI; __shared__ float selB[4];
    const int t = threadIdx.x;
    int cnt = *cntp; if (cnt > 6144) cnt = 6144;
    float s[6]; int id6[6]; float bx[6][4]; float ar[6];
#pragma unroll
    for (int k = 0; k < 6; ++k) {
        int slot = t + k * 1024;
        if (slot < cnt) {
            s[k] = pools[slot]; id6[k] = pooli[slot];
            bx[k][0] = poolb[slot * 4 + 0]; bx[k][1] = poolb[slot * 4 + 1];
            bx[k][2] = poolb[slot * 4 + 2]; bx[k][3] = poolb[slot * 4 + 3];
            ar[k] = (bx[k][2] - bx[k][0]) * (bx[k][3] - bx[k][1]);
        } else {
            s[k] = -INFINITY; id6[k] = 0x7fffffff;
            bx[k][0] = bx[k][1] = bx[k][2] = bx[k][3] = 0.f; ar[k] = 0.f;
        }
    }
    for (int it = 0; it < NROI; ++it) {
        float bs = -INFINITY; int bi = 0x7fffffff;
#pragma unroll
        for (int k = 0; k < 6; ++k)
            if (s[k] > bs || (s[k] == bs && id6[k] < bi)) { bs = s[k]; bi = id6[k]; }
#pragma unroll
        for (int off = 1; off < 64; off <<= 1) {
            float os = __shfl_xor(bs, off);
            int oi = __shfl_xor(bi, off);
            if (os > bs || (os == bs && oi < bi)) { bs = os; bi = oi; }
        }
        if ((t & 63) == 0) { wvS[t >> 6] = bs; wvI[t >> 6] = bi; }
        __syncthreads();
        if (t == 0) {
            float fs = wvS[0]; int fi = wvI[0];
            for (int wv = 1; wv < 16; ++wv) {
                float os = wvS[wv]; int oi = wvI[wv];
                if (os > fs || (os == fs && oi < fi)) { fs = os; fi = oi; }
            }
            selS = fs; selI = fi;
            selB[0] = selB[1] = selB[2] = selB[3] = 0.f;
        }
        __syncthreads();
        const float fs = selS; const int fi = selI;
        if (fs > -INFINITY) {
#pragma unroll
            for (int k = 0; k < 6; ++k)
                if (id6[k] == fi) {
                    selB[0] = bx[k][0]; selB[1] = bx[k][1];
                    selB[2] = bx[k][2]; selB[3] = bx[k][3];
                }
        }
        __syncthreads();
        const bool ok = (fs > -INFINITY);
        if (t < 4) rois[it * 4 + t] = ok ? selB[t] : 0.f;
        if (t == 4) okf[it] = ok ? 1.f : 0.f;
        if (ok) {
            float q0 = selB[0], q1 = selB[1], q2 = selB[2], q3 = selB[3];
            float qa = (q2 - q0) * (q3 - q1);
#pragma unroll
            for (int k = 0; k < 6; ++k) {
                if (s[k] > -INFINITY) {
                    float yy1 = fmaxf(q0, bx[k][0]), xx1 = fmaxf(q1, bx[k][1]);
                    float yy2 = fminf(q2, bx[k][2]), xx2 = fminf(q3, bx[k][3]);
                    float inter = fmaxf(yy2 - yy1, 0.f) * fmaxf(xx2 - xx1, 0.f);
                    float iou = inter / (qa + ar[k] - inter + 1e-9f);
                    if (iou > 0.7f) s[k] = -INFINITY;
                }
            }
        }
        __syncthreads();
    }
}

// ---------------- K5: ROI align (7x7, sr=2) ----------------
__global__ __launch_bounds__(256) void k5_roialign(const float* __restrict__ feat,
                                                   const float* __restrict__ rois,
                                                   float* __restrict__ pooled) {
    const int r = blockIdx.x;
    const int t = threadIdx.x;
    if (t >= 245) return;
    const int op = t % 49, cg = t / 49;        // out pixel, channel group 0..4
    const int sy = op / 7, sx = op % 7;
    const float r0 = rois[r * 4 + 0] * 0.0625f, r1 = rois[r * 4 + 1] * 0.0625f;
    const float r2 = rois[r * 4 + 2] * 0.0625f, r3 = rois[r * 4 + 3] * 0.0625f;
    const float bh = (r2 - r0) / 7.f, bw = (r3 - r1) / 7.f;
    int iy0[2], iy1[2], ix0[2], ix1[2];
    float ly[2], lx[2];
#pragma unroll
    for (int a = 0; a < 2; ++a) {
        float offy = ((float)(2 * sy + a) + 0.5f) * 0.5f;
        float ys = r0 + bh * offy;
        float yf = floorf(ys);
        ly[a] = ys - yf;
        int y0 = (int)yf;
        iy0[a] = min(max(y0, 0), 49);
        iy1[a] = min(max(y0 + 1, 0), 49);
        float offx = ((float)(2 * sx + a) + 0.5f) * 0.5f;
        float xs = r1 + bw * offx;
        float xf = floorf(xs);
        lx[a] = xs - xf;
        int x0 = (int)xf;
        ix0[a] = min(max(x0, 0), 49);
        ix1[a] = min(max(x0 + 1, 0), 49);
    }
    for (int c = cg; c < 512; c += 5) {
        const float* fb = feat + c * 2500;
        float vs[2][2];
#pragma unroll
        for (int a = 0; a < 2; ++a) {
#pragma unroll
            for (int b = 0; b < 2; ++b) {
                float wy0 = 1.f - ly[a], wx0 = 1.f - lx[b];
                float v = fb[iy0[a] * 50 + ix0[b]] * (wy0 * wx0)
                        + fb[iy0[a] * 50 + ix1[b]] * (wy0 * lx[b])
                        + fb[iy1[a] * 50 + ix0[b]] * (ly[a] * wx0)
                        + fb[iy1[a] * 50 + ix1[b]] * (ly[a] * lx[b]);
                vs[a][b] = v;
            }
        }
        pooled[r * 25088 + c * 49 + op] =
            ((vs[0][0] + vs[0][1]) + (vs[1][0] + vs[1][1])) * 0.25f;
    }
}

// ---------------- K6/K7: f32 GEMM, M=128 fixed, bias + optional relu ----------------
template <bool RELU>
__global__ __launch_bounds__(256) void gemm128(const float* __restrict__ A,   // [128][K]
                                               const float* __restrict__ B,   // [K][N]
                                               const float* __restrict__ bias,
                                               float* __restrict__ C,         // [128][N]
                                               int N, int K) {
    __shared__ float As[32][132];
    __shared__ float Bs[32][16];
    const int n0 = blockIdx.x * 16;
    const int t = threadIdx.x;
    const int tn = t & 15, tm = t >> 4;   // tm*8.. +7 rows
    float acc[8];
#pragma unroll
    for (int i = 0; i < 8; ++i) acc[i] = 0.f;
    for (int k0 = 0; k0 < K; k0 += 32) {
#pragma unroll
        for (int i = 0; i < 16; ++i) {
            int l = t + i * 256;               // 0..4095
            int kk = l & 31, m = l >> 5;
            As[kk][m] = A[m * K + k0 + kk];
        }
#pragma unroll
        for (int i = 0; i < 2; ++i) {
            int l = t + i * 256;
            int nn = l & 15, kk = l >> 4;
            Bs[kk][nn] = B[(size_t)(k0 + kk) * N + n0 + nn];
        }
        __syncthreads();
#pragma unroll
        for (int kk = 0; kk < 32; ++kk) {
            float b = Bs[kk][tn];
            float4 a0 = *(const float4*)&As[kk][tm * 8];
            float4 a1 = *(const float4*)&As[kk][tm * 8 + 4];
            acc[0] = fmaf(a0.x, b, acc[0]);
            acc[1] = fmaf(a0.y, b, acc[1]);
            acc[2] = fmaf(a0.z, b, acc[2]);
            acc[3] = fmaf(a0.w, b, acc[3]);
            acc[4] = fmaf(a1.x, b, acc[4]);
            acc[5] = fmaf(a1.y, b, acc[5]);
            acc[6] = fmaf(a1.z, b, acc[6]);
            acc[7] = fmaf(a1.w, b, acc[7]);
        }
        __syncthreads();
    }
    const int n = n0 + tn;
    const float bv = bias[n];
#pragma unroll
    for (int i = 0; i < 8; ++i) {
        float v = acc[i] + bv;
        if (RELU) v = fmaxf(v, 0.f);
        C[(size_t)(tm * 8 + i) * N + n] = v;
    }
}

// ---------------- K8: heads + softmax + decode + outputs ----------------
__global__ __launch_bounds__(256) void k8_head(const float* __restrict__ X,   // [128][4096]
                                               const float* __restrict__ Wc,
                                               const float* __restrict__ bc,
                                               const float* __restrict__ Wb,
                                               const float* __restrict__ bb,
                                               const float* __restrict__ rois,
                                               const float* __restrict__ okf,
                                               float* __restrict__ out) {
    __shared__ float xs[4096];
    __shared__ float lg[21];
    __shared__ float dl[84];
    __shared__ float red[2];
    const int m = blockIdx.x, t = threadIdx.x;
    for (int i = t; i < 4096; i += 256) xs[i] = X[m * 4096 + i];
    __syncthreads();
    if (t < 105) {
        float acc = 0.f;
        if (t < 21) {
#pragma unroll 4
            for (int k = 0; k < 4096; ++k) acc = fmaf(xs[k], Wc[k * 21 + t], acc);
            lg[t] = acc + bc[t];
        } else {
            int n = t - 21;
#pragma unroll 4
            for (int k = 0; k < 4096; ++k) acc = fmaf(xs[k], Wb[k * 84 + n], acc);
            dl[n] = acc + bb[n];
        }
    }
    __syncthreads();
    if (t == 0) {
        float mx = lg[0];
        for (int j = 1; j < 21; ++j) mx = fmaxf(mx, lg[j]);
        red[0] = mx;
    }
    __syncthreads();
    if (t < 21) lg[t] = expf(lg[t] - red[0]);
    __syncthreads();
    if (t == 0) {
        float sm = 0.f;
        for (int j = 0; j < 21; ++j) sm += lg[j];
        red[1] = sm;
    }
    __syncthreads();
    if (t < 20) {
        const int j = t + 1;
        const float prob = lg[j] / red[1];
        const float r0 = rois[m * 4 + 0], r1 = rois[m * 4 + 1];
        const float r2 = rois[m * 4 + 2], r3 = rois[m * 4 + 3];
        const float hh = r2 - r0, ww = r3 - r1;
        const float cy = r0 + 0.5f * hh, cx = r1 + 0.5f * ww;
        const float dy = dl[j * 4 + 0] / 10.f;
        const float dx = dl[j * 4 + 1] / 10.f;
        const float dh = fminf(fmaxf(dl[j * 4 + 2] / 5.f, -BBOX_CLIP), BBOX_CLIP);
        const float dw = fminf(fmaxf(dl[j * 4 + 3] / 5.f, -BBOX_CLIP), BBOX_CLIP);
        const float pcy = cy + dy * hh, pcx = cx + dx * ww;
        const float ph = hh * expf(dh), pw = ww * expf(dw);
        const float b0 = pcy - 0.5f * ph, b1 = pcx - 0.5f * pw;
        const float b2 = pcy + 0.5f * ph, b3 = pcx + 0.5f * pw;
        const int o = m * 20 + t;
        out[o] = prob;                                   // scores_out
        out[2560 + o * 4 + 0] = b0;                      // boxes
        out[2560 + o * 4 + 1] = b1;
        out[2560 + o * 4 + 2] = b2;
        out[2560 + o * 4 + 3] = b3;
        out[12800 + o] = (float)t;                       // cls_idxes
        const bool kp = (prob > 0.05f) && ((b2 - b0) >= 1.f) && ((b3 - b1) >= 1.f)
                        && (okf[m] != 0.f);
        out[15360 + o] = kp ? 1.f : 0.f;                 // keep
    }
    if (t < 4) out[17920 + m * 4 + t] = rois[m * 4 + t]; // rois128
}

// ---------------- host launcher ----------------
extern "C" void kernel_launch(void* const* d_in, const int* in_sizes, int n_in,
                              void* d_out, int out_size, void* d_ws, size_t ws_size,
                              hipStream_t stream) {
    const float* feat = (const float*)d_in[0];
    const float* anch = (const float*)d_in[1];
    const float* cw   = (const float*)d_in[2];
    const float* cb   = (const float*)d_in[3];
    const float* clsw = (const float*)d_in[4];
    const float* clsb = (const float*)d_in[5];
    const float* regw = (const float*)d_in[6];
    const float* regb = (const float*)d_in[7];
    const float* W1   = (const float*)d_in[8];
    const float* b1   = (const float*)d_in[9];
    const float* W2   = (const float*)d_in[10];
    const float* b2   = (const float*)d_in[11];
    const float* Wc   = (const float*)d_in[12];
    const float* bc   = (const float*)d_in[13];
    const float* Wb   = (const float*)d_in[14];
    const float* bb   = (const float*)d_in[15];
    float* ws = (float*)d_ws;
    float* out = (float*)d_out;

    k0_transpose<<<dim3(72, 8), 256, 0, stream>>>(cw, ws + OFF_WT);
    k1_conv<<<dim3(40, 8), 256, 0, stream>>>(feat, ws + OFF_WT, cb, ws + OFF_H);
    k2_rpnhead<<<528, 256, 0, stream>>>(ws + OFF_H, clsw, clsb, regw, regb,
                                        ws + OFF_CLS, ws + OFF_REG);
    k3_decode<<<88, 256, 0, stream>>>(ws + OFF_CLS, ws + OFF_REG, anch,
                                      ws + OFF_SCORE, ws + OFF_PBOX);
    k4a_select<<<1, 1024, 0, stream>>>(ws + OFF_SCORE, ws + OFF_PBOX,
                                       ws + OFF_POOLS, ws + OFF_POOLB,
                                       (int*)(ws + OFF_POOLI), (int*)(ws + OFF_CNT));
    k4b_nms<<<1, 1024, 0, stream>>>(ws + OFF_POOLS, ws + OFF_POOLB,
                                    (const int*)(ws + OFF_POOLI),
                                    (const int*)(ws + OFF_CNT),
                                    ws + OFF_ROIS, ws + OFF_OK);
    k5_roialign<<<128, 256, 0, stream>>>(feat, ws + OFF_ROIS, ws + OFF_POOLED);
    gemm128<true><<<256, 256, 0, stream>>>(ws + OFF_POOLED, W1, b1, ws + OFF_X1,
                                           4096, 25088);
    gemm128<true><<<256, 256, 0, stream>>>(ws + OFF_X1, W2, b2, ws + OFF_X2,
                                           4096, 4096);
    k8_head<<<128, 256, 0, stream>>>(ws + OFF_X2, Wc, bc, Wb, bb,
                                     ws + OFF_ROIS, ws + OFF_OK, out);
}